// Round 9
// baseline (448.656 us; speedup 1.0000x reference)
//
#include <hip/hip_runtime.h>
#include <hip/hip_bf16.h>

typedef __attribute__((ext_vector_type(8))) short bf16x8;
typedef __attribute__((ext_vector_type(4))) short s16x4;
typedef __attribute__((ext_vector_type(4))) float f32x4;

// LDS (bytes): [0,32768) X dbuf 2x[64 rows][64 f32], linear dest, source XOR-swizzled.
// shorts: Q[64][72]@16384  K[64][72]@20992  VT[64][72]@25600  (end 30208 shorts = 60416 B)
// PT/Y overlay per wave: Q region + wid*1152 (PT [64][16], Y [16][72]) -- wave-private rows.
#define QSOFF 16384
#define KSOFF 20992
#define VSOFF 25600
#define LDSB  60416

__device__ __forceinline__ short f2b(float f) {
    __hip_bfloat16 h = __float2bfloat16(f);
    return __builtin_bit_cast(short, h);
}

__global__ void cvt_weights(const float* __restrict__ W1, const float* __restrict__ W2,
                            short* __restrict__ w1b, short* __restrict__ w2b) {
    int i = blockIdx.x * 256 + threadIdx.x;
    if (i < 192 * 768) w1b[i] = f2b(W1[i]);
    if (i < 768 * 64)  w2b[i] = f2b(W2[i]);
}

__device__ __forceinline__ void gload_lds16(const float* g, unsigned char* l) {
    __builtin_amdgcn_global_load_lds(
        (const __attribute__((address_space(1))) void*)g,
        (__attribute__((address_space(3))) void*)l, 16, 0, 0);
}

#define VMW(n)  asm volatile("s_waitcnt vmcnt(" #n ")" ::: "memory")
#define LGKM0() asm volatile("s_waitcnt lgkmcnt(0)" ::: "memory")
#define SBAR()  __builtin_amdgcn_sched_barrier(0)

__device__ __forceinline__ void stage_chunk(const float* XG, int kc, int b,
                                            unsigned char* L, int wid, int lane) {
    #pragma unroll
    for (int j = 0; j < 4; ++j) {
        int rr = (wid * 4 + j) * 4 + (lane >> 4);
        int ss = lane & 15;
        const float* gsrc = XG + rr * 768 + kc * 64 + ((ss ^ (rr & 15)) << 2);
        gload_lds16(gsrc, &L[(size_t)b * 16384 + (wid * 4 + j) * 1024]);
    }
}

__device__ __forceinline__ void wpref(int kc, bf16x8* W, const short* __restrict__ W1b,
                                      int wid, int g, int c) {
    #pragma unroll
    for (int ks = 0; ks < 2; ++ks)
        #pragma unroll
        for (int oi = 0; oi < 3; ++oi)
            W[ks * 3 + oi] = *(const bf16x8*)(W1b + (16 * (wid + 4 * oi) + c) * 768
                                              + kc * 64 + ks * 32 + 8 * g);
}

__device__ __forceinline__ void compute_chunk(int b, const bf16x8* W, f32x4* acc1,
                                              const unsigned char* L, int g, int c) {
    const unsigned char* Lb = &L[(size_t)b * 16384];
    #pragma unroll
    for (int ks = 0; ks < 2; ++ks) {
        bf16x8 a[4];
        #pragma unroll
        for (int rt = 0; rt < 4; ++rt) {
            int r = 16 * rt + c;
            int s0 = (8 * ks + 2 * g) ^ (r & 15);
            int s1 = ((8 * ks + 2 * g) ^ 1) ^ (r & 15);
            f32x4 lo = *(const f32x4*)(Lb + r * 256 + s0 * 16);
            f32x4 hi = *(const f32x4*)(Lb + r * 256 + s1 * 16);
            a[rt][0] = f2b(lo[0]); a[rt][1] = f2b(lo[1]);
            a[rt][2] = f2b(lo[2]); a[rt][3] = f2b(lo[3]);
            a[rt][4] = f2b(hi[0]); a[rt][5] = f2b(hi[1]);
            a[rt][6] = f2b(hi[2]); a[rt][7] = f2b(hi[3]);
        }
        #pragma unroll
        for (int oi = 0; oi < 3; ++oi)
            #pragma unroll
            for (int rt = 0; rt < 4; ++rt)
                acc1[rt * 3 + oi] = __builtin_amdgcn_mfma_f32_16x16x32_bf16(
                    a[rt], W[ks * 3 + oi], acc1[rt * 3 + oi], 0, 0, 0);
    }
}

// proj2 piece of the PREVIOUS window: units 4pc..4pc+3 (use P2), then load P2 for pc+1.
__device__ __forceinline__ void piece(int pc, bf16x8* P2, bf16x8 ay0, bf16x8 ay1,
                                      float* __restrict__ oprev,
                                      const short* __restrict__ W2b,
                                      const float* __restrict__ b2, int g, int c) {
    const f32x4 z4 = {0.f, 0.f, 0.f, 0.f};
    #pragma unroll
    for (int q = 0; q < 4; ++q) {
        int o = 16 * (4 * pc + q) + c;
        float bb = b2[o];
        f32x4 t = __builtin_amdgcn_mfma_f32_16x16x32_bf16(ay0, P2[2 * q], z4, 0, 0, 0);
        t = __builtin_amdgcn_mfma_f32_16x16x32_bf16(ay1, P2[2 * q + 1], t, 0, 0, 0);
        #pragma unroll
        for (int r = 0; r < 4; ++r)
            oprev[(size_t)(4 * g + r) * 768 + o] = t[r] + bb;
    }
    if (pc + 1 < 12) {
        #pragma unroll
        for (int q = 0; q < 4; ++q) {
            int off = (16 * (4 * (pc + 1) + q) + c) * 64;
            P2[2 * q]     = *(const bf16x8*)(W2b + off + 8 * g);
            P2[2 * q + 1] = *(const bf16x8*)(W2b + off + 32 + 8 * g);
        }
    }
}

// queue accounting (newer-than-stage(kc)):
//  no pieces: kc<11 -> W6+stg4=10 ; kc=11 -> 6
//  pieces: kc=0 -> stg4+P2(8)+W6=18 ; 1..10 -> W6+stg4+piece28=38 ; kc=11 -> W6+piece28=34
template<bool PIECES>
__device__ __forceinline__ void pipe_iter(int kc, int b, bf16x8* Wc, bf16x8* Wn,
        const float* xg, f32x4* acc1, bf16x8* P2, bf16x8 ay0, bf16x8 ay1,
        float* oprev, const short* __restrict__ W1b, const short* __restrict__ W2b,
        const float* __restrict__ b2, unsigned char* L, int wid, int lane, int g, int c) {
    if (PIECES) { if (kc == 0) VMW(18); else if (kc == 11) VMW(34); else VMW(38); }
    else        { if (kc == 11) VMW(6);  else VMW(10); }
    SBAR(); __builtin_amdgcn_s_barrier(); SBAR();
    compute_chunk(b, Wc, acc1, L, g, c);
    if (kc + 1 < 12) wpref(kc + 1, Wn, W1b, wid, g, c);
    LGKM0(); SBAR(); __builtin_amdgcn_s_barrier(); SBAR();
    if (kc + 2 < 12) stage_chunk(xg, kc + 2, b, L, wid, lane);
    if (PIECES) piece(kc, P2, ay0, ay1, oprev, W2b, b2, g, c);
}

// 4-window persistent chain: proj2(w-1) interleaved into proj1(w)'s pipe.
__global__ __launch_bounds__(256, 2)
void tiny_att4(const float* __restrict__ x, const float* __restrict__ b1,
               const float* __restrict__ b2, const short* __restrict__ W1b,
               const short* __restrict__ W2b, float* __restrict__ out, int nwin) {
    __shared__ __align__(16) unsigned char L[LDSB];
    short* S = (short*)L;
    const int tid  = threadIdx.x;
    const int wid  = tid >> 6;
    const int lane = tid & 63;
    const int g    = lane >> 4;
    const int c    = lane & 15;
    const int base = blockIdx.x * 4;
    if (base >= nwin) return;
    const int nw = min(4, nwin - base);
    const f32x4 z4 = {0.f, 0.f, 0.f, 0.f};
    const float B1q = b1[16 * wid + c];
    const float B1k = b1[64 + 16 * wid + c];
    const float B1w = b1[128 + 16 * wid + c];
    const int pwv = QSOFF + wid * 1152;   // PT/Y overlay base (shorts), wave-private Q rows

    bf16x8 Wa[6], Wb[6], P2[8];
    bf16x8 ay0 = {}, ay1 = {};
    float* oprev = nullptr;

    const float* xg0 = x + (size_t)base * 49152;
    stage_chunk(xg0, 0, 0, L, wid, lane);
    stage_chunk(xg0, 1, 1, L, wid, lane);
    wpref(0, Wa, W1b, wid, g, c);

    #pragma unroll 1
    for (int i = 0; i < nw; ++i) {
        const float* xcur = x + (size_t)(base + i) * 49152;
        f32x4 acc1[12];
        #pragma unroll
        for (int t = 0; t < 12; ++t) acc1[t] = z4;

        if (i > 0) {
            #pragma unroll 1
            for (int kc = 0; kc < 12; kc += 2) {
                pipe_iter<true>(kc,     0, Wa, Wb, xcur, acc1, P2, ay0, ay1, oprev,
                                W1b, W2b, b2, L, wid, lane, g, c);
                pipe_iter<true>(kc + 1, 1, Wb, Wa, xcur, acc1, P2, ay0, ay1, oprev,
                                W1b, W2b, b2, L, wid, lane, g, c);
            }
        } else {
            #pragma unroll 1
            for (int kc = 0; kc < 12; kc += 2) {
                pipe_iter<false>(kc,     0, Wa, Wb, xcur, acc1, P2, ay0, ay1, oprev,
                                 W1b, W2b, b2, L, wid, lane, g, c);
                pipe_iter<false>(kc + 1, 1, Wb, Wa, xcur, acc1, P2, ay0, ay1, oprev,
                                 W1b, W2b, b2, L, wid, lane, g, c);
            }
        }

        // ---- bias + QKV -> LDS (acc1[rt*3+oi]: row 16rt+4g+r, col 16(wid+4oi)+c) ----
        #pragma unroll
        for (int rt = 0; rt < 4; ++rt) {
            f32x4 vq = acc1[rt * 3 + 0];
            f32x4 vk = acc1[rt * 3 + 1];
            f32x4 vv = acc1[rt * 3 + 2];
            #pragma unroll
            for (int r = 0; r < 4; ++r) {
                S[QSOFF + (16 * rt + 4 * g + r) * 72 + 16 * wid + c] = f2b(vq[r] + B1q);
                S[KSOFF + (16 * rt + 4 * g + r) * 72 + 16 * wid + c] = f2b(vk[r] + B1k);
            }
            s16x4 sv;
            sv[0] = f2b(vv[0] + B1w); sv[1] = f2b(vv[1] + B1w);
            sv[2] = f2b(vv[2] + B1w); sv[3] = f2b(vv[3] + B1w);
            *(s16x4*)&S[VSOFF + (16 * wid + c) * 72 + 16 * rt + 4 * g] = sv;
        }
        if (i + 1 < nw) {   // keep read stream alive through attn
            const float* xn = x + (size_t)(base + i + 1) * 49152;
            stage_chunk(xn, 0, 0, L, wid, lane);
            stage_chunk(xn, 1, 1, L, wid, lane);
        }
        __syncthreads();    // QKV visible

        // ---- S = Q K^T (q-rows 16wid..+15) ----
        f32x4 sc[4];
        #pragma unroll
        for (int mt = 0; mt < 4; ++mt) sc[mt] = z4;
        #pragma unroll
        for (int ks = 0; ks < 2; ++ks) {
            bf16x8 aq = *(const bf16x8*)&S[QSOFF + (16 * wid + c) * 72 + 32 * ks + 8 * g];
            #pragma unroll
            for (int mt = 0; mt < 4; ++mt) {
                bf16x8 bk = *(const bf16x8*)&S[KSOFF + (16 * mt + c) * 72 + 32 * ks + 8 * g];
                sc[mt] = __builtin_amdgcn_mfma_f32_16x16x32_bf16(aq, bk, sc[mt], 0, 0, 0);
            }
        }
        // ---- softmax ----
        float p[4][4];
        const float kS = 0.125f * 1.44269504088896f;
        #pragma unroll
        for (int r = 0; r < 4; ++r) {
            float m0 = fmaxf(fmaxf(sc[0][r], sc[1][r]), fmaxf(sc[2][r], sc[3][r]));
            m0 = fmaxf(m0, __shfl_xor(m0, 1));
            m0 = fmaxf(m0, __shfl_xor(m0, 2));
            m0 = fmaxf(m0, __shfl_xor(m0, 4));
            m0 = fmaxf(m0, __shfl_xor(m0, 8));
            float s0 = 0.f, pr[4];
            #pragma unroll
            for (int mt = 0; mt < 4; ++mt) { pr[mt] = exp2f((sc[mt][r] - m0) * kS); s0 += pr[mt]; }
            s0 += __shfl_xor(s0, 1);
            s0 += __shfl_xor(s0, 2);
            s0 += __shfl_xor(s0, 4);
            s0 += __shfl_xor(s0, 8);
            float inv = __builtin_amdgcn_rcpf(s0);
            #pragma unroll
            for (int mt = 0; mt < 4; ++mt) p[mt][r] = pr[mt] * inv;
        }
        // ---- P^T -> overlay (own Q rows; wave-private, no barrier) ----
        #pragma unroll
        for (int mt = 0; mt < 4; ++mt) {
            s16x4 sv;
            sv[0] = f2b(p[mt][0]); sv[1] = f2b(p[mt][1]);
            sv[2] = f2b(p[mt][2]); sv[3] = f2b(p[mt][3]);
            *(s16x4*)&S[pwv + (16 * mt + c) * 16 + 4 * g] = sv;
        }
        // ---- Y^T = V^T @ P^T ----
        f32x4 y4[4];
        #pragma unroll
        for (int it = 0; it < 4; ++it) y4[it] = z4;
        #pragma unroll
        for (int ks = 0; ks < 2; ++ks) {
            bf16x8 pb;
            #pragma unroll
            for (int j = 0; j < 8; ++j)
                pb[j] = S[pwv + (32 * ks + 8 * g + j) * 16 + c];
            #pragma unroll
            for (int it = 0; it < 4; ++it) {
                bf16x8 av = *(const bf16x8*)&S[VSOFF + (16 * it + c) * 72 + 32 * ks + 8 * g];
                y4[it] = __builtin_amdgcn_mfma_f32_16x16x32_bf16(av, pb, y4[it], 0, 0, 0);
            }
        }
        // ---- Y repack (overlay reuse) -> ay fragments ----
        #pragma unroll
        for (int it = 0; it < 4; ++it) {
            s16x4 sv;
            sv[0] = f2b(y4[it][0]); sv[1] = f2b(y4[it][1]);
            sv[2] = f2b(y4[it][2]); sv[3] = f2b(y4[it][3]);
            *(s16x4*)&S[pwv + c * 72 + 16 * it + 4 * g] = sv;
        }
        ay0 = *(const bf16x8*)&S[pwv + c * 72 + 8 * g];
        ay1 = *(const bf16x8*)&S[pwv + c * 72 + 32 + 8 * g];
        oprev = out + ((size_t)(base + i) * 64 + 16 * wid) * 768;

        if (i + 1 < nw) {   // P2 + W1 prefetch for next loop (counted in VMW(18))
            #pragma unroll
            for (int q = 0; q < 4; ++q) {
                int off = (16 * q + c) * 64;
                P2[2 * q]     = *(const bf16x8*)(W2b + off + 8 * g);
                P2[2 * q + 1] = *(const bf16x8*)(W2b + off + 32 + 8 * g);
            }
            wpref(0, Wa, W1b, wid, g, c);
        } else {            // final window: plain proj2
            #pragma unroll 4
            for (int u = 0; u < 48; ++u) {
                int o = 16 * u + c;
                bf16x8 bw0 = *(const bf16x8*)(W2b + o * 64 + 8 * g);
                bf16x8 bw1 = *(const bf16x8*)(W2b + o * 64 + 32 + 8 * g);
                f32x4 t = __builtin_amdgcn_mfma_f32_16x16x32_bf16(ay0, bw0, z4, 0, 0, 0);
                t = __builtin_amdgcn_mfma_f32_16x16x32_bf16(ay1, bw1, t, 0, 0, 0);
                float bb = b2[o];
                #pragma unroll
                for (int r = 0; r < 4; ++r)
                    oprev[(size_t)(4 * g + r) * 768 + o] = t[r] + bb;
            }
        }
    }
}

// Correctness-only fallback (ws too small): naive fp32 per-window kernel.
__global__ __launch_bounds__(256)
void tiny_att_fb(const float* __restrict__ x, const float* __restrict__ W1,
                 const float* __restrict__ b1, const float* __restrict__ W2,
                 const float* __restrict__ b2, float* __restrict__ out) {
    __shared__ float QKV[64][200];
    __shared__ float Y[64][64];
    const int win = blockIdx.x, tid = threadIdx.x;
    const float* xw = x + (size_t)win * 49152;
    for (int t = tid; t < 64 * 192; t += 256) {
        int n = t / 192, o = t % 192;
        float s = b1[o];
        for (int k = 0; k < 768; ++k) s += xw[n * 768 + k] * W1[o * 768 + k];
        QKV[n][o] = s;
    }
    __syncthreads();
    if (tid < 64) {
        int q = tid;
        float scr[64], m = -1e30f;
        for (int k = 0; k < 64; ++k) {
            float s = 0;
            for (int d = 0; d < 64; ++d) s += QKV[q][d] * QKV[k][64 + d];
            scr[k] = s * 0.125f; m = fmaxf(m, scr[k]);
        }
        float den = 0;
        for (int k = 0; k < 64; ++k) { scr[k] = __expf(scr[k] - m); den += scr[k]; }
        float inv = 1.f / den;
        for (int d = 0; d < 64; ++d) {
            float y = 0;
            for (int k = 0; k < 64; ++k) y += scr[k] * QKV[k][128 + d];
            Y[q][d] = y * inv;
        }
    }
    __syncthreads();
    for (int t = tid; t < 64 * 768; t += 256) {
        int n = t / 768, o = t % 768;
        float s = b2[o];
        for (int d = 0; d < 64; ++d) s += Y[n][d] * W2[o * 64 + d];
        out[(size_t)win * 49152 + t] = s;
    }
}

extern "C" void kernel_launch(void* const* d_in, const int* in_sizes, int n_in,
                              void* d_out, int out_size, void* d_ws, size_t ws_size,
                              hipStream_t stream) {
    const float* x  = (const float*)d_in[0];
    const float* W1 = (const float*)d_in[1];
    const float* b1 = (const float*)d_in[2];
    const float* W2 = (const float*)d_in[3];
    const float* b2 = (const float*)d_in[4];
    float* out = (float*)d_out;
    const int nwin = in_sizes[0] / (64 * 768);   // 2048 windows
    const size_t need = (size_t)(192 * 768 + 768 * 64) * sizeof(short);
    if (ws_size >= need) {
        short* w1b = (short*)d_ws;
        short* w2b = w1b + 192 * 768;
        cvt_weights<<<576, 256, 0, stream>>>(W1, W2, w1b, w2b);
        tiny_att4<<<(nwin + 3) / 4, 256, 0, stream>>>(x, b1, b2, w1b, w2b, out, nwin);
    } else {
        tiny_att_fb<<<nwin, 256, 0, stream>>>(x, W1, b1, W2, b2, out);
    }
}

// Round 10
// 198.010 us; speedup vs baseline: 2.2658x; 2.2658x over previous
//
#include <hip/hip_runtime.h>
#include <hip/hip_bf16.h>

typedef __attribute__((ext_vector_type(8))) short bf16x8;
typedef __attribute__((ext_vector_type(4))) short s16x4;
typedef __attribute__((ext_vector_type(4))) float f32x4;

// LDS layout (bytes):
//  [0, 32768)     X double-buffer: 2 x [64 rows][64 f32] LINEAR (global_load_lds dest),
//                 16B-slot index XOR-swizzled on the SOURCE side (both-sides rule)
//  [32768, 49152) QK bf16 [64][128] (Q cols 0..63, K cols 64..127)
//  post-proj1 alias into X region (shorts): VT[64][72] @0 ; per-wave scratch @4608+wid*1280
#define XBUF(b)   ((b) * 16384)
#define QK_SH     16384
#define LDS_BYTES 49152

__device__ __forceinline__ short f2b(float f) {
    __hip_bfloat16 h = __float2bfloat16(f);
    return __builtin_bit_cast(short, h);
}

// Fragment-major weight packing. W1: 12 o-tiles x 24 k32-instances, each a 512-short
// block laid out lane-major (lane*8 shorts = the lane's bf16x8 B-fragment).
// W2: 48 o-tiles x 2 k-halves, same 512-short blocks.
// => kernel-side fragment load = base + lane*16B : fully coalesced (8 cache lines,
//    vs 64 scattered lines for the row-major layout).
__global__ void cvt_weights(const float* __restrict__ W1, const float* __restrict__ W2,
                            short* __restrict__ w1b, short* __restrict__ w2b) {
    int i = blockIdx.x * 256 + threadIdx.x;          // 576 blocks x 256 = 147456
    if (i < 192 * 768) {
        int B = i >> 9, r = i & 511;
        int lane = r >> 3, j = r & 7;
        int g = lane >> 4, c = lane & 15;
        int ot = B / 24, k32 = B - ot * 24;
        w1b[i] = f2b(W1[(16 * ot + c) * 768 + k32 * 32 + 8 * g + j]);
    }
    if (i < 768 * 64) {
        int B = i >> 9, r = i & 511;
        int lane = r >> 3, j = r & 7;
        int g = lane >> 4, c = lane & 15;
        int u = B >> 1, half = B & 1;
        w2b[i] = f2b(W2[(16 * u + c) * 64 + half * 32 + 8 * g + j]);
    }
}

__device__ __forceinline__ void gload_lds16(const float* g, unsigned char* l) {
    __builtin_amdgcn_global_load_lds(
        (const __attribute__((address_space(1))) void*)g,
        (__attribute__((address_space(3))) void*)l, 16, 0, 0);
}

#define VMWAIT(n) asm volatile("s_waitcnt vmcnt(" #n ")" ::: "memory")

// Stage 64-col f32 chunk kc -> X buffer b (4 gload_lds/wave, dest wave-uniform+lane*16).
#define STAGE_CHUNK(kc, b) do {                                                     \
    _Pragma("unroll")                                                               \
    for (int j = 0; j < 4; ++j) {                                                   \
        int rr = (wid * 4 + j) * 4 + (lane >> 4);                                   \
        int ss = lane & 15;                                                         \
        const float* gsrc = xg + rr * 768 + (kc) * 64 + ((ss ^ (rr & 15)) << 2);    \
        gload_lds16(gsrc, &L[XBUF(b) + (wid * 4 + j) * 1024]);                      \
    }                                                                               \
} while (0)

// W1 fragment prefetch: 6 coalesced 1KB loads (o-tiles wid, 4+wid, 8+wid; k-halves 0,1)
#define WPREF(kc, W) do {                                                           \
    _Pragma("unroll")                                                               \
    for (int ks = 0; ks < 2; ++ks)                                                  \
        _Pragma("unroll")                                                           \
        for (int oi = 0; oi < 3; ++oi)                                              \
            W[ks*3+oi] = *(const bf16x8*)(W1b +                                     \
                ((wid + 4*oi) * 24 + (kc)*2 + ks) * 512 + lane * 8);                \
} while (0)

#define COMPUTE(kc, b, W) do {                                                      \
    const unsigned char* Lb = &L[XBUF(b)];                                          \
    _Pragma("unroll")                                                               \
    for (int ks = 0; ks < 2; ++ks) {                                                \
        bf16x8 a[4];                                                                \
        _Pragma("unroll")                                                           \
        for (int rt = 0; rt < 4; ++rt) {                                            \
            int r = 16*rt + c;                                                      \
            int s0 = (8*ks + 2*g) ^ (r & 15);                                       \
            int s1 = (8*ks + 2*g + 1) ^ (r & 15);                                   \
            f32x4 lo = *(const f32x4*)(Lb + r*256 + s0*16);                         \
            f32x4 hi = *(const f32x4*)(Lb + r*256 + s1*16);                         \
            a[rt][0]=f2b(lo[0]); a[rt][1]=f2b(lo[1]);                               \
            a[rt][2]=f2b(lo[2]); a[rt][3]=f2b(lo[3]);                               \
            a[rt][4]=f2b(hi[0]); a[rt][5]=f2b(hi[1]);                               \
            a[rt][6]=f2b(hi[2]); a[rt][7]=f2b(hi[3]);                               \
        }                                                                           \
        _Pragma("unroll")                                                           \
        for (int oi = 0; oi < 3; ++oi)                                              \
            _Pragma("unroll")                                                       \
            for (int rt = 0; rt < 4; ++rt)                                          \
                acc1[rt*3+oi] = __builtin_amdgcn_mfma_f32_16x16x32_bf16(            \
                    a[rt], W[ks*3+oi], acc1[rt*3+oi], 0, 0, 0);                     \
    }                                                                               \
} while (0)

// steady: newer-than-stage(kc) = W(kc)6 + stage(kc+1)4 -> vmcnt(10); kc=11 -> 6
#define PIPE_ITER(kc, b, Wc, Wn) do {                                               \
    if ((kc) != 11) { VMWAIT(10); } else { VMWAIT(6); }                             \
    __builtin_amdgcn_sched_barrier(0);                                              \
    __builtin_amdgcn_s_barrier();                                                   \
    __builtin_amdgcn_sched_barrier(0);                                              \
    COMPUTE(kc, b, Wc);                                                             \
    if ((kc) + 1 < 12) WPREF((kc)+1, Wn);                                           \
    asm volatile("s_waitcnt lgkmcnt(0)" ::: "memory");                              \
    __builtin_amdgcn_sched_barrier(0);                                              \
    __builtin_amdgcn_s_barrier();                                                   \
    __builtin_amdgcn_sched_barrier(0);                                              \
    if ((kc) + 2 < 12) STAGE_CHUNK((kc)+2, b);                                      \
} while (0)

__global__ __launch_bounds__(256, 3)
void tiny_att(const float* __restrict__ x, const float* __restrict__ b1v,
              const float* __restrict__ b2v, const short* __restrict__ W1b,
              const short* __restrict__ W2b, float* __restrict__ out) {
    __shared__ __align__(16) unsigned char L[LDS_BYTES];
    short* S = (short*)L;
    const int tid  = threadIdx.x;
    const int wid  = tid >> 6;
    const int lane = tid & 63;
    const int g    = lane >> 4;
    const int c    = lane & 15;
    const int win  = blockIdx.x;
    const float* xg = x + (size_t)win * (64 * 768);
    const f32x4 zero4 = {0.f, 0.f, 0.f, 0.f};

    // ---------------- proj1: QKV[64][192] = X @ W1^T, async-pipelined ----------------
    f32x4 acc1[12];
    #pragma unroll
    for (int i = 0; i < 12; ++i) acc1[i] = zero4;

    bf16x8 Wa[6], Wb[6];
    STAGE_CHUNK(0, 0);
    STAGE_CHUNK(1, 1);
    WPREF(0, Wa);

    #pragma unroll 1
    for (int kc = 0; kc < 12; kc += 2) {
        PIPE_ITER(kc,     0, Wa, Wb);
        PIPE_ITER(kc + 1, 1, Wb, Wa);
    }
    __syncthreads();   // X region dead -> VT/PT alias it

    // ---------------- bias + QKV -> LDS ----------------
    #pragma unroll
    for (int oi = 0; oi < 3; ++oi) {
        int ot = wid + 4 * oi;
        int o  = 16 * ot + c;
        float bias = b1v[o];
        #pragma unroll
        for (int rt = 0; rt < 4; ++rt) {
            f32x4 v = acc1[rt * 3 + oi];
            if (oi < 2) {        // Q (o<64), K (64..127): [n][o], stride 128
                #pragma unroll
                for (int r = 0; r < 4; ++r)
                    S[QK_SH + (16 * rt + 4 * g + r) * 128 + o] = f2b(v[r] + bias);
            } else {             // VT[d][n], stride 72, base 0
                int d = o - 128;
                s16x4 sv;
                sv[0] = f2b(v[0] + bias); sv[1] = f2b(v[1] + bias);
                sv[2] = f2b(v[2] + bias); sv[3] = f2b(v[3] + bias);
                *(s16x4*)&S[d * 72 + 16 * rt + 4 * g] = sv;
            }
        }
    }
    __syncthreads();

    // ---------------- S = Q K^T (wave: q-rows 16wid..16wid+15) ----------------
    f32x4 sc[4];
    #pragma unroll
    for (int mt = 0; mt < 4; ++mt) sc[mt] = zero4;
    #pragma unroll
    for (int ks = 0; ks < 2; ++ks) {
        bf16x8 aq = *(const bf16x8*)&S[QK_SH + (16 * wid + c) * 128 + 32 * ks + 8 * g];
        #pragma unroll
        for (int mt = 0; mt < 4; ++mt) {
            bf16x8 bk = *(const bf16x8*)&S[QK_SH + (16 * mt + c) * 128 + 64 + 32 * ks + 8 * g];
            sc[mt] = __builtin_amdgcn_mfma_f32_16x16x32_bf16(aq, bk, sc[mt], 0, 0, 0);
        }
    }

    // ---------------- softmax ----------------
    float p[4][4];
    const float kS = 0.125f * 1.44269504088896f;
    #pragma unroll
    for (int r = 0; r < 4; ++r) {
        float m0 = fmaxf(fmaxf(sc[0][r], sc[1][r]), fmaxf(sc[2][r], sc[3][r]));
        m0 = fmaxf(m0, __shfl_xor(m0, 1));
        m0 = fmaxf(m0, __shfl_xor(m0, 2));
        m0 = fmaxf(m0, __shfl_xor(m0, 4));
        m0 = fmaxf(m0, __shfl_xor(m0, 8));
        float s0 = 0.f;
        float pr[4];
        #pragma unroll
        for (int mt = 0; mt < 4; ++mt) { pr[mt] = exp2f((sc[mt][r] - m0) * kS); s0 += pr[mt]; }
        s0 += __shfl_xor(s0, 1);
        s0 += __shfl_xor(s0, 2);
        s0 += __shfl_xor(s0, 4);
        s0 += __shfl_xor(s0, 8);
        float inv = __builtin_amdgcn_rcpf(s0);
        #pragma unroll
        for (int mt = 0; mt < 4; ++mt) p[mt][r] = pr[mt] * inv;
    }

    // ---------------- P^T -> per-wave scratch ----------------
    const int ptb = 4608 + wid * 1280;
    #pragma unroll
    for (int mt = 0; mt < 4; ++mt) {
        s16x4 sv;
        sv[0] = f2b(p[mt][0]); sv[1] = f2b(p[mt][1]);
        sv[2] = f2b(p[mt][2]); sv[3] = f2b(p[mt][3]);
        *(s16x4*)&S[ptb + (16 * mt + c) * 20 + 4 * g] = sv;
    }

    // ---------------- Y^T = V^T @ P^T ----------------
    f32x4 y4[4];
    #pragma unroll
    for (int it = 0; it < 4; ++it) y4[it] = zero4;
    #pragma unroll
    for (int ks = 0; ks < 2; ++ks) {
        bf16x8 pb;
        #pragma unroll
        for (int j = 0; j < 8; ++j)
            pb[j] = S[ptb + (32 * ks + 8 * g + j) * 20 + c];
        #pragma unroll
        for (int it = 0; it < 4; ++it) {
            bf16x8 av = *(const bf16x8*)&S[(16 * it + c) * 72 + 32 * ks + 8 * g];
            y4[it] = __builtin_amdgcn_mfma_f32_16x16x32_bf16(av, pb, y4[it], 0, 0, 0);
        }
    }
    // Y repack via scratch (aliases PT; this wave's PT reads done)
    #pragma unroll
    for (int it = 0; it < 4; ++it) {
        s16x4 sv;
        sv[0] = f2b(y4[it][0]); sv[1] = f2b(y4[it][1]);
        sv[2] = f2b(y4[it][2]); sv[3] = f2b(y4[it][3]);
        *(s16x4*)&S[ptb + c * 72 + 16 * it + 4 * g] = sv;
    }
    bf16x8 ay0 = *(const bf16x8*)&S[ptb + c * 72 + 8 * g];
    bf16x8 ay1 = *(const bf16x8*)&S[ptb + c * 72 + 32 + 8 * g];

    // ---------------- proj2: out[16 rows][768] = Y @ W2^T + b2 ----------------
    float* orow = out + ((size_t)win * 64 + 16 * wid) * 768;
    #pragma unroll 1
    for (int ch = 0; ch < 6; ++ch) {
        f32x4 a2[8];
        #pragma unroll
        for (int i = 0; i < 8; ++i) a2[i] = zero4;
        #pragma unroll
        for (int oi = 0; oi < 8; ++oi) {
            int u = ch * 8 + oi;
            bf16x8 bw0 = *(const bf16x8*)(W2b + (2 * u) * 512 + lane * 8);
            a2[oi] = __builtin_amdgcn_mfma_f32_16x16x32_bf16(ay0, bw0, a2[oi], 0, 0, 0);
            bf16x8 bw1 = *(const bf16x8*)(W2b + (2 * u + 1) * 512 + lane * 8);
            a2[oi] = __builtin_amdgcn_mfma_f32_16x16x32_bf16(ay1, bw1, a2[oi], 0, 0, 0);
        }
        #pragma unroll
        for (int oi = 0; oi < 8; ++oi) {
            int o = 16 * (ch * 8 + oi) + c;
            float bias = b2v[o];
            #pragma unroll
            for (int r = 0; r < 4; ++r)
                orow[(size_t)(4 * g + r) * 768 + o] = a2[oi][r] + bias;
        }
    }
}

// Correctness-only fallback (ws too small): naive fp32 per-window kernel.
__global__ __launch_bounds__(256)
void tiny_att_fb(const float* __restrict__ x, const float* __restrict__ W1,
                 const float* __restrict__ b1, const float* __restrict__ W2,
                 const float* __restrict__ b2, float* __restrict__ out) {
    __shared__ float QKV[64][200];
    __shared__ float Y[64][64];
    const int win = blockIdx.x, tid = threadIdx.x;
    const float* xw = x + (size_t)win * 49152;
    for (int t = tid; t < 64 * 192; t += 256) {
        int n = t / 192, o = t % 192;
        float s = b1[o];
        for (int k = 0; k < 768; ++k) s += xw[n * 768 + k] * W1[o * 768 + k];
        QKV[n][o] = s;
    }
    __syncthreads();
    if (tid < 64) {
        int q = tid;
        float scr[64], m = -1e30f;
        for (int k = 0; k < 64; ++k) {
            float s = 0;
            for (int d = 0; d < 64; ++d) s += QKV[q][d] * QKV[k][64 + d];
            scr[k] = s * 0.125f; m = fmaxf(m, scr[k]);
        }
        float den = 0;
        for (int k = 0; k < 64; ++k) { scr[k] = __expf(scr[k] - m); den += scr[k]; }
        float inv = 1.f / den;
        for (int d = 0; d < 64; ++d) {
            float y = 0;
            for (int k = 0; k < 64; ++k) y += scr[k] * QKV[k][128 + d];
            Y[q][d] = y * inv;
        }
    }
    __syncthreads();
    for (int t = tid; t < 64 * 768; t += 256) {
        int n = t / 768, o = t % 768;
        float s = b2[o];
        for (int d = 0; d < 64; ++d) s += Y[n][d] * W2[o * 64 + d];
        out[(size_t)win * 49152 + t] = s;
    }
}

extern "C" void kernel_launch(void* const* d_in, const int* in_sizes, int n_in,
                              void* d_out, int out_size, void* d_ws, size_t ws_size,
                              hipStream_t stream) {
    const float* x  = (const float*)d_in[0];
    const float* W1 = (const float*)d_in[1];
    const float* b1 = (const float*)d_in[2];
    const float* W2 = (const float*)d_in[3];
    const float* b2 = (const float*)d_in[4];
    float* out = (float*)d_out;
    const int nwin = in_sizes[0] / (64 * 768);   // 2048 windows
    const size_t need = (size_t)(192 * 768 + 768 * 64) * sizeof(short);
    if (ws_size >= need) {
        short* w1b = (short*)d_ws;
        short* w2b = w1b + 192 * 768;
        cvt_weights<<<576, 256, 0, stream>>>(W1, W2, w1b, w2b);
        tiny_att<<<nwin, 256, 0, stream>>>(x, b1, b2, w1b, w2b, out);
    } else {
        tiny_att_fb<<<nwin, 256, 0, stream>>>(x, W1, b1, W2, b2, out);
    }
}